// Round 3
// baseline (239.000 us; speedup 1.0000x reference)
//
#include <hip/hip_runtime.h>

// PCEN: M_t = (1-s) M_{t-1} + s x_t (IIR along T, T=2048 contiguous per row),
// out = (x*(eps+M)^-alpha + bias)^power - bias^power.
//
// Register-only version (no LDS, no barriers): one wave per row. Lane owns
// float4 groups at elements 4*lane + 256*k (k=0..7) -> coalesced loads AND
// stores. Scan hierarchy:
//   1. per-lane 4-elem local scan per chunk (zero init)        [FMA chain]
//   2. Kogge-Stone wave scan per chunk, multiplier A^4         [8 indep scans]
//   3. serial chunk-carry chain across k=0..7, multiplier A^256
//   4. carry into lane's group = excl_scan + A^(4*lane) * C_k; re-run local
//      recurrence fused with epilogue, direct float4 store.
// Transcendentals via __builtin_amdgcn_{exp2f,logf} (v_exp_f32/v_log_f32,
// both base-2) — __exp2f/__log2f spellings collide with glibc math.h.

#define T_LEN 2048

__device__ __forceinline__ float fast_exp2(float x) { return __builtin_amdgcn_exp2f(x); }
__device__ __forceinline__ float fast_log2(float x) { return __builtin_amdgcn_logf(x); }

__global__ __launch_bounds__(256) void pcen_kernel(
    const float* __restrict__ x,
    const float* __restrict__ alpha_p,
    const float* __restrict__ power_p,
    const float* __restrict__ bias_p,
    float* __restrict__ out)
{
    const int wave = threadIdx.x >> 6;
    const int lane = threadIdx.x & 63;
    const int row  = (blockIdx.x << 2) | wave;

    const float alpha = alpha_p[0];
    const float power = power_p[0];
    const float bias  = bias_p[0];

    const float A = 0.985f;   // 1 - SMOOTH
    const float S = 0.015f;   // SMOOTH

    const float* xr  = x   + (size_t)row * T_LEN;
    float*       orw = out + (size_t)row * T_LEN;

    // ---- coalesced float4 loads: lane owns elems 4*lane + 256*k ----
    float4 xv[8];
#pragma unroll
    for (int k = 0; k < 8; ++k)
        xv[k] = *reinterpret_cast<const float4*>(xr + 4 * lane + 256 * k);

    // ---- per-lane local scan ends (zero initial state per chunk) ----
    float s[8];
#pragma unroll
    for (int k = 0; k < 8; ++k) {
        float m = 0.0f;
        m = A * m + S * xv[k].x;
        m = A * m + S * xv[k].y;
        m = A * m + S * xv[k].z;
        m = A * m + S * xv[k].w;
        s[k] = m;
    }

    // ---- Kogge-Stone inclusive wave scan per chunk (multiplier A^4) ----
    // All 8 chunk scans are independent -> interleaved for ILP.
    float g = A; g *= g; g *= g;   // A^4
#pragma unroll
    for (int d = 1; d < 64; d <<= 1) {
#pragma unroll
        for (int k = 0; k < 8; ++k) {
            const float so = __shfl_up(s[k], d, 64);
            if (lane >= d) s[k] += g * so;
        }
        g *= g;
    }

    // A^(4*lane) for applying the chunk carry at this lane's group start
    const float log2A = fast_log2(A);
    const float A4L   = fast_exp2((float)(4 * lane) * log2A);
    // A^256
    float A256 = A; 
#pragma unroll
    for (int i = 0; i < 8; ++i) A256 *= A256;   // A^2,4,8,16,32,64,128,256

    const float bias_pow = fast_exp2(power * fast_log2(bias));

    // ---- per-chunk: carry-in, fused local recurrence + epilogue, store ----
    float C = 0.0f;   // IIR state entering chunk k
#pragma unroll
    for (int k = 0; k < 8; ++k) {
        float excl = __shfl_up(s[k], 1, 64);
        if (lane == 0) excl = 0.0f;
        const float endk = __shfl(s[k], 63, 64);

        float m = excl + A4L * C;   // state entering this lane's 4-group
        float4 o;
#pragma unroll
        for (int j = 0; j < 4; ++j) {
            const float xx = (&xv[k].x)[j];
            m = A * m + S * xx;
            const float den = 1e-9f + m;
            const float t   = xx * fast_exp2(-alpha * fast_log2(den)) + bias;
            (&o.x)[j] = fast_exp2(power * fast_log2(t)) - bias_pow;
        }
        *reinterpret_cast<float4*>(orw + 4 * lane + 256 * k) = o;

        C = endk + A256 * C;
    }
}

extern "C" void kernel_launch(void* const* d_in, const int* in_sizes, int n_in,
                              void* d_out, int out_size, void* d_ws, size_t ws_size,
                              hipStream_t stream) {
    const float* x       = (const float*)d_in[0];
    const float* alpha_p = (const float*)d_in[1];
    const float* power_p = (const float*)d_in[2];
    const float* bias_p  = (const float*)d_in[3];
    float* out           = (float*)d_out;

    const int nrows  = in_sizes[0] / T_LEN;   // 16384, divisible by 4
    const int blocks = nrows / 4;

    pcen_kernel<<<blocks, 256, 0, stream>>>(x, alpha_p, power_p, bias_p, out);
}